// Round 4
// baseline (480.461 us; speedup 1.0000x reference)
//
#include <hip/hip_runtime.h>
#include <hip/hip_bf16.h>

#define BATCH 1024
#define NV 5023
#define NJOINT 5
#define NLMK 51
#define N3 (NV*3)        // 15069
#define KBETA 400
#define KTOT 448         // 400 betas + 36 pose_feature + 12 zero pad

#define BM 64
#define BN 48
#define LDT 40           // LDS k-pitch (bf16) for As/Bs; 80 B rows (16B multiple)
#define LDP 52           // LDS pitch (f32) for acc tile

typedef __attribute__((ext_vector_type(8))) short short8;
typedef __attribute__((ext_vector_type(4))) float floatx4;

// ---------------- workspace byte offsets (total ~1.19 MB) ----------------
#define WS_JS      0          // 6000 f32
#define WS_BASEJ   24064      // 15 f32
#define WS_REG     24512      // 1 f32
#define WS_FLAGS   24520      // 2 ints: [0]=f32 inputs, [1]=int64 lmk idx
#define WS_AMAT    24576      // 1024*60 f32   -> ends 270336
#define WS_ACT     270336     // 1024*448 bf16 -> ends 1187840

// dtype-agnostic scalar load
__device__ __forceinline__ float ldf(const void* p, long i, int f32) {
    if (f32) return ((const float*)p)[i];
    return __bfloat162float(((const __hip_bfloat16*)p)[i]);
}
// dtype-agnostic 8-elem load -> bf16 short8 (i must be 8-elem aligned)
__device__ __forceinline__ short8 ld8bf(const void* p, long i, int f32) {
    if (f32) {
        const float* q = (const float*)p + i;
        short8 r;
#pragma unroll
        for (int j = 0; j < 8; ++j) {
            __hip_bfloat16 h = __float2bfloat16(q[j]);
            r[j] = *reinterpret_cast<short*>(&h);
        }
        return r;
    }
    return *(const short8*)((const __hip_bfloat16*)p + i);
}
// dtype-agnostic store
__device__ __forceinline__ void stf(void* p, long i, float v, int f32) {
    if (f32) ((float*)p)[i] = v;
    else ((__hip_bfloat16*)p)[i] = __float2bfloat16(v);
}

__global__ void k_zero(float* p, int n) {
    int i = blockIdx.x * blockDim.x + threadIdx.x;
    if (i < n) p[i] = 0.f;
}

// Probe input dtypes. If shape_params is f32, its even halfwords read as bf16
// have random exponents -> max blows past 1e4 (p ~ 1-1e-16). If genuinely
// bf16 ~N(0,1), max stays tiny.
__global__ void k_probe(const void* shape_p, const void* lmk_idx, int* flags) {
    __shared__ float mx[64];
    int tid = threadIdx.x;
    unsigned short h = ((const unsigned short*)shape_p)[2 * tid];
    union { unsigned short u; __hip_bfloat16 b; } cv; cv.u = h;
    float v = fabsf(__bfloat162float(cv.b));
    if (v != v) v = 3.4e38f;               // NaN counts as "huge"
    mx[tid] = v;
    __syncthreads();
    if (tid == 0) {
        float m = 0.f;
        for (int i = 0; i < 64; ++i) m = fmaxf(m, mx[i]);
        flags[0] = (m > 1e4f) ? 1 : 0;
        int i64 = 1;
        const int* q = (const int*)lmk_idx;
        for (int i = 0; i < 25; ++i) if (q[2*i+1] != 0) i64 = 0;
        flags[1] = i64;
    }
}

// JS[j][k][l] = sum_v Jreg[j][v]*shapedirs[v][k][l]; baseJ = Jreg @ v_template
__global__ void k_js(const void* __restrict__ Jreg,
                     const void* __restrict__ shapedirs,
                     const void* __restrict__ v_template,
                     const int* __restrict__ flags,
                     float* __restrict__ JS, float* __restrict__ baseJ) {
    int f32 = flags[0];
    int k = blockIdx.x;        // 0..2
    int vc = blockIdx.y;       // 0..15
    int tid = threadIdx.x;     // 0..255
    int v0 = vc * 314, v1 = min(NV, v0 + 314);
    int l2 = tid + 256;        // second l; 400 == template col
    float acc1[NJOINT] = {0,0,0,0,0};
    float acc2[NJOINT] = {0,0,0,0,0};
    for (int v = v0; v < v1; ++v) {
        float s1 = ldf(shapedirs, (long)v*1200 + k*400 + tid, f32);
        float s2 = 0.f;
        if (l2 < 400)       s2 = ldf(shapedirs, (long)v*1200 + k*400 + l2, f32);
        else if (l2 == 400) s2 = ldf(v_template, v*3 + k, f32);
#pragma unroll
        for (int j = 0; j < NJOINT; ++j) {
            float jr = ldf(Jreg, j*NV + v, f32);
            acc1[j] += jr * s1;
            acc2[j] += jr * s2;
        }
    }
#pragma unroll
    for (int j = 0; j < NJOINT; ++j) {
        atomicAdd(&JS[j*1200 + k*400 + tid], acc1[j]);
        if (l2 < 400)       atomicAdd(&JS[j*1200 + k*400 + l2], acc2[j]);
        else if (l2 == 400) atomicAdd(&baseJ[j*3 + k], acc2[j]);
    }
}

// Per-batch: betas->Act(bf16), joints, rodrigues, chain, A matrices, reg
__global__ __launch_bounds__(64) void k_batch(
        const void* __restrict__ shape_p, const void* __restrict__ expr_p,
        const void* __restrict__ grot, const void* __restrict__ neck,
        const void* __restrict__ jaw,  const void* __restrict__ eye,
        const float* __restrict__ JS, const float* __restrict__ baseJ,
        const int* __restrict__ flags,
        __hip_bfloat16* __restrict__ Act, float* __restrict__ Amat, float* __restrict__ reg) {
    int f32 = flags[0];
    int b = blockIdx.x, tid = threadIdx.x;
    __shared__ float betas[400];
    __shared__ float Rm[NJOINT][9];
    __shared__ float joints[NJOINT][3];
    __shared__ float Gm[NJOINT][12];

    for (int i = tid; i < 400; i += 64) {
        float v = (i < 300) ? ldf(shape_p, b*300 + i, f32)
                            : ldf(expr_p, b*100 + i - 300, f32);
        betas[i] = v;
        Act[b*KTOT + i] = __float2bfloat16(v);
    }
    if (tid >= 36 && tid < 48) Act[b*KTOT + 400 + tid] = __float2bfloat16(0.f);
    __syncthreads();

    if (tid < 15) {
        int j = tid / 3, k = tid - 3*j;
        float s = baseJ[tid];
        const float* js = &JS[j*1200 + k*400];
        for (int l = 0; l < 400; ++l) s += js[l] * betas[l];
        joints[j][k] = s;
    }
    if (tid < NJOINT) {
        int j = tid;
        float r[3];
        for (int c = 0; c < 3; ++c) {
            if (j == 0)      r[c] = ldf(grot, b*3 + c, f32);
            else if (j == 1) r[c] = ldf(neck, b*3 + c, f32);
            else if (j == 2) r[c] = ldf(jaw,  b*3 + c, f32);
            else if (j == 3) r[c] = ldf(eye,  b*6 + c, f32);
            else             r[c] = ldf(eye,  b*6 + 3 + c, f32);
        }
        float a0 = r[0] + 1e-8f, a1 = r[1] + 1e-8f, a2 = r[2] + 1e-8f;
        float angle = sqrtf(a0*a0 + a1*a1 + a2*a2);
        float inv = 1.0f / angle;
        float rx = r[0]*inv, ry = r[1]*inv, rz = r[2]*inv;
        float s = sinf(angle), c = cosf(angle);
        float K[9] = {0.f, -rz, ry,  rz, 0.f, -rx,  -ry, rx, 0.f};
        float K2[9];
        for (int rr = 0; rr < 3; ++rr)
            for (int cc = 0; cc < 3; ++cc) {
                float t = 0.f;
                for (int m = 0; m < 3; ++m) t += K[rr*3+m] * K[m*3+cc];
                K2[rr*3+cc] = t;
            }
        for (int i2 = 0; i2 < 9; ++i2) {
            float id = (i2 == 0 || i2 == 4 || i2 == 8) ? 1.f : 0.f;
            Rm[j][i2] = id + s*K[i2] + (1.f - c)*K2[i2];
        }
    }
    __syncthreads();

    if (tid < 36) {
        int i = tid / 9 + 1, rc = tid - (tid/9)*9;
        float id = (rc == 0 || rc == 4 || rc == 8) ? 1.f : 0.f;
        Act[b*KTOT + 400 + tid] = __float2bfloat16(Rm[i][rc] - id);
    }
    if (tid == 0) {
        for (int rr = 0; rr < 3; ++rr) {
            for (int cc = 0; cc < 3; ++cc) Gm[0][rr*4+cc] = Rm[0][rr*3+cc];
            Gm[0][rr*4+3] = joints[0][rr];
        }
        const int par[NJOINT] = {-1, 0, 1, 1, 1};
        for (int j = 1; j < NJOINT; ++j) {
            int p = par[j];
            float rel[3];
            for (int c2 = 0; c2 < 3; ++c2) rel[c2] = joints[j][c2] - joints[p][c2];
            for (int rr = 0; rr < 3; ++rr) {
                for (int cc = 0; cc < 3; ++cc) {
                    float t = 0.f;
                    for (int m = 0; m < 3; ++m) t += Gm[p][rr*4+m] * Rm[j][m*3+cc];
                    Gm[j][rr*4+cc] = t;
                }
                float t = Gm[p][rr*4+3];
                for (int m = 0; m < 3; ++m) t += Gm[p][rr*4+m] * rel[m];
                Gm[j][rr*4+3] = t;
            }
        }
    }
    __syncthreads();

    if (tid < 60) {
        int j = tid / 12, e = tid - j*12, rr = e / 4, cc = e - rr*4;
        float val = Gm[j][e];
        if (cc == 3)
            for (int m = 0; m < 3; ++m) val -= Gm[j][rr*4+m] * joints[j][m];
        Amat[b*60 + tid] = val;
    }

    float part = 0.f;
    for (int i = tid; i < 400; i += 64) part += betas[i]*betas[i];
    part *= 0.001f;
    if (tid == 0) {
        float nn = 0.f, jj = 0.f;
        for (int c = 0; c < 3; ++c) {
            float nv = ldf(neck, b*3+c, f32);
            float jv = ldf(jaw,  b*3+c, f32);
            nn += nv*nv; jj += jv*jv;
        }
        part += 100.f*nn + 0.001f*jj;
    }
    for (int off = 32; off; off >>= 1) part += __shfl_down(part, off);
    if (tid == 0) atomicAdd(reg, part);
}

// Fused GEMM + LBS. B streams from shapedirs ([N3][400] row-major) for
// K-steps 0..11; ragged tail (shapedirs cols 384..399 + posedirs^T + pad)
// in persistent LDS tile Bs2. v_template added in the epilogue.
__global__ __launch_bounds__(256) void k_gemm_lbs(
        const __hip_bfloat16* __restrict__ Act,
        const void* __restrict__ shapedirs,
        const void* __restrict__ posedirs,
        const void* __restrict__ v_template,
        const float* __restrict__ Amat,
        const void* __restrict__ weights,
        const void* __restrict__ transl,
        const int* __restrict__ flags,
        void* __restrict__ out) {
    __shared__ __align__(16) __hip_bfloat16 As[BM * LDT];
    __shared__ __align__(16) __hip_bfloat16 Bs[BN * LDT];
    __shared__ __align__(16) __hip_bfloat16 Bs2[BN * 64];
    __shared__ float tile[BM * LDP];
    __shared__ float Al[BM * 60];
    __shared__ float wl[16 * NJOINT];

    int f32 = flags[0];
    int tid = threadIdx.x;
    int wave = tid >> 6, lane = tid & 63;
    int fr = lane & 15, quad = lane >> 4;
    int n0 = blockIdx.x * BN, m0 = blockIdx.y * BM;
    int v0 = blockIdx.x * 16;

    for (int i = tid; i < BM * 60; i += 256) Al[i] = Amat[m0 * 60 + i];
    if (tid < 80) {
        int v = v0 + tid / NJOINT;
        wl[tid] = (v < NV) ? ldf(weights, v * NJOINT + tid % NJOINT, f32) : 0.f;
    }
    for (int i = tid; i < BN * 64; i += 256) {
        int n = i >> 6, kk = i & 63;
        int nc = min(n0 + n, N3 - 1);
        float val = 0.f;
        if (kk < 16)      val = ldf(shapedirs, (long)nc*KBETA + 384 + kk, f32);
        else if (kk < 52) val = ldf(posedirs, (long)(kk-16)*N3 + nc, f32);
        Bs2[n*64 + kk] = __float2bfloat16(val);
    }

    floatx4 acc[3];
#pragma unroll
    for (int t = 0; t < 3; ++t) acc[t] = (floatx4){0.f, 0.f, 0.f, 0.f};

    int r = tid >> 2;               // 0..63
    int cg = (tid & 3) * 8;
    for (int s = 0; s < 14; ++s) {
        int k0 = s * 32;
        *(short8*)&As[r*LDT + cg] = *(const short8*)&Act[(m0 + r)*KTOT + k0 + cg];
        if (s < 12 && tid < 192) {
            int nr = min(n0 + r, N3 - 1);
            *(short8*)&Bs[r*LDT + cg] = ld8bf(shapedirs, (long)nr*KBETA + k0 + cg, f32);
        }
        __syncthreads();
        short8 a = *(short8*)&As[(wave*16 + fr)*LDT + quad*8];
#pragma unroll
        for (int t = 0; t < 3; ++t) {
            short8 bb;
            if (s < 12) bb = *(short8*)&Bs[(t*16 + fr)*LDT + quad*8];
            else        bb = *(short8*)&Bs2[(t*16 + fr)*64 + (s - 12)*32 + quad*8];
            acc[t] = __builtin_amdgcn_mfma_f32_16x16x32_bf16(a, bb, acc[t], 0, 0, 0);
        }
        __syncthreads();
    }

#pragma unroll
    for (int t = 0; t < 3; ++t)
#pragma unroll
        for (int rr = 0; rr < 4; ++rr)
            tile[(wave*16 + quad*4 + rr)*LDP + t*16 + fr] = acc[t][rr];
    __syncthreads();

    int vloc = tid & 15, mrow = tid >> 4;
    int v = v0 + vloc;
    if (v < NV) {
        float tpl0 = ldf(v_template, v*3 + 0, f32);
        float tpl1 = ldf(v_template, v*3 + 1, f32);
        float tpl2 = ldf(v_template, v*3 + 2, f32);
        float w0 = wl[vloc*NJOINT+0], w1 = wl[vloc*NJOINT+1], w2 = wl[vloc*NJOINT+2];
        float w3 = wl[vloc*NJOINT+3], w4 = wl[vloc*NJOINT+4];
#pragma unroll
        for (int it = 0; it < 4; ++it) {
            int m = mrow + 16*it;
            float p0 = tile[m*LDP + vloc*3 + 0] + tpl0;
            float p1 = tile[m*LDP + vloc*3 + 1] + tpl1;
            float p2 = tile[m*LDP + vloc*3 + 2] + tpl2;
            const float* A = &Al[m*60];
#pragma unroll
            for (int c = 0; c < 3; ++c) {
                float t0 = w0*A[0*12+c*4+0] + w1*A[1*12+c*4+0] + w2*A[2*12+c*4+0] + w3*A[3*12+c*4+0] + w4*A[4*12+c*4+0];
                float t1 = w0*A[0*12+c*4+1] + w1*A[1*12+c*4+1] + w2*A[2*12+c*4+1] + w3*A[3*12+c*4+1] + w4*A[4*12+c*4+1];
                float t2 = w0*A[0*12+c*4+2] + w1*A[1*12+c*4+2] + w2*A[2*12+c*4+2] + w3*A[3*12+c*4+2] + w4*A[4*12+c*4+2];
                float t3 = w0*A[0*12+c*4+3] + w1*A[1*12+c*4+3] + w2*A[2*12+c*4+3] + w3*A[3*12+c*4+3] + w4*A[4*12+c*4+3];
                float val = t0*p0 + t1*p1 + t2*p2 + t3 + ldf(transl, (m0+m)*3 + c, f32);
                stf(out, ((long)(m0+m)*NV + v)*3 + c, val, f32);
            }
        }
    }
}

// Landmarks from final vertices (exact for any bary sum), plus flame_reg.
__global__ __launch_bounds__(64) void k_lmk(const void* __restrict__ verts,
                                            const void* __restrict__ bary,
                                            const int* __restrict__ faces,
                                            const void* __restrict__ lmk_idx,
                                            const void* __restrict__ transl,
                                            const float* __restrict__ reg,
                                            const int* __restrict__ flags,
                                            void* __restrict__ out) {
    int f32 = flags[0], i64 = flags[1];
    int b = blockIdx.x, tid = threadIdx.x;
    if (b == 0 && tid == 63)
        stf(out, (long)BATCH*NV*3 + (long)BATCH*NLMK*3, reg[0], f32);
    if (tid >= NLMK) return;
    int f = i64 ? (int)((const long long*)lmk_idx)[tid]
                : ((const int*)lmk_idx)[tid];
    float acc[3] = {0.f, 0.f, 0.f};
    float bsum = 0.f;
    for (int fi = 0; fi < 3; ++fi) {
        int vi = faces[f*3 + fi];
        float bc = ldf(bary, tid*3 + fi, f32);
        bsum += bc;
#pragma unroll
        for (int c = 0; c < 3; ++c)
            acc[c] += bc * ldf(verts, ((long)b*NV + vi)*3 + c, f32);
    }
#pragma unroll
    for (int c = 0; c < 3; ++c) {
        float val = acc[c] + (1.f - bsum) * ldf(transl, b*3 + c, f32);
        stf(out, (long)BATCH*NV*3 + ((long)b*NLMK + tid)*3 + c, val, f32);
    }
}

extern "C" void kernel_launch(void* const* d_in, const int* in_sizes, int n_in,
                              void* d_out, int out_size, void* d_ws, size_t ws_size,
                              hipStream_t stream) {
    const void* shape_p   = d_in[0];
    const void* expr_p    = d_in[1];
    const void* grot      = d_in[2];
    const void* neck      = d_in[3];
    const void* jaw       = d_in[4];
    const void* eye       = d_in[5];
    const void* transl    = d_in[6];
    const void* v_templ   = d_in[7];
    const void* shapedirs = d_in[8];
    const void* posedirs  = d_in[9];
    const void* Jreg      = d_in[10];
    const void* weights   = d_in[11];
    const void* bary      = d_in[12];
    const int*  faces     = (const int*)d_in[14];
    const void* lmk_idx   = d_in[15];

    char* ws = (char*)d_ws;
    float* JS      = (float*)(ws + WS_JS);
    float* baseJ   = (float*)(ws + WS_BASEJ);
    float* reg     = (float*)(ws + WS_REG);
    int*   flags   = (int*)(ws + WS_FLAGS);
    float* Amat    = (float*)(ws + WS_AMAT);
    __hip_bfloat16* Act = (__hip_bfloat16*)(ws + WS_ACT);

    k_zero<<<24, 256, 0, stream>>>((float*)ws, 6144);
    k_probe<<<1, 64, 0, stream>>>(shape_p, lmk_idx, flags);
    k_js<<<dim3(3, 16), 256, 0, stream>>>(Jreg, shapedirs, v_templ, flags, JS, baseJ);
    k_batch<<<BATCH, 64, 0, stream>>>(shape_p, expr_p, grot, neck, jaw, eye,
                                      JS, baseJ, flags, Act, Amat, reg);
    k_gemm_lbs<<<dim3((N3 + BN - 1)/BN, BATCH/BM), 256, 0, stream>>>(
        Act, shapedirs, posedirs, v_templ, Amat, weights, transl, flags, d_out);
    k_lmk<<<BATCH, 64, 0, stream>>>(d_out, bary, faces, lmk_idx, transl, reg, flags, d_out);
}

// Round 5
// 317.105 us; speedup vs baseline: 1.5151x; 1.5151x over previous
//
#include <hip/hip_runtime.h>
#include <hip/hip_bf16.h>

#define BATCH 1024
#define NV 5023
#define NJOINT 5
#define NLMK 51
#define N3 (NV*3)        // 15069
#define NPADB 15072      // N3 padded to multiple of 48
#define KBETA 400
#define KTOT 448         // 400 betas + 36 pose_feature + 12 zero pad

#define BM 256           // batches per block (4 waves x 64)
#define BN 48            // output cols per block = 16 vertices
#define LDP 52           // LDS pitch (f32) for acc tile

typedef __attribute__((ext_vector_type(8))) short short8;
typedef __attribute__((ext_vector_type(4))) float floatx4;

// ---------------- workspace byte offsets ----------------
#define WS_JS      0          // 6000 f32
#define WS_BASEJ   24064      // 15 f32
#define WS_REG     24512      // 1 f32
#define WS_FLAGS   24520      // 2 ints
#define WS_AMAT    24576      // 1024*60 f32   -> ends 270336
#define WS_ACT     270336     // 1024*448 bf16 -> ends 1187840
#define WS_WB      1187840    // 15072*448 bf16 -> ends 14692352
#define WS_MIN     1187840
#define WS_FULL    14692352

// dtype-agnostic scalar load
__device__ __forceinline__ float ldf(const void* p, long i, int f32) {
    if (f32) return ((const float*)p)[i];
    return __bfloat162float(((const __hip_bfloat16*)p)[i]);
}
// dtype-agnostic 8-elem load -> bf16 short8
__device__ __forceinline__ short8 ld8bf(const void* p, long i, int f32) {
    if (f32) {
        const float* q = (const float*)p + i;
        short8 r;
#pragma unroll
        for (int j = 0; j < 8; ++j) {
            __hip_bfloat16 h = __float2bfloat16(q[j]);
            r[j] = *reinterpret_cast<short*>(&h);
        }
        return r;
    }
    return *(const short8*)((const __hip_bfloat16*)p + i);
}
__device__ __forceinline__ void stf(void* p, long i, float v, int f32) {
    if (f32) ((float*)p)[i] = v;
    else ((__hip_bfloat16*)p)[i] = __float2bfloat16(v);
}

__global__ void k_zero(float* p, int n) {
    int i = blockIdx.x * blockDim.x + threadIdx.x;
    if (i < n) p[i] = 0.f;
}

// dtype probe (see round 3): f32-as-bf16 halfwords blow past 1e4 w.p. ~1.
__global__ void k_probe(const void* shape_p, const void* lmk_idx, int* flags) {
    __shared__ float mx[64];
    int tid = threadIdx.x;
    unsigned short h = ((const unsigned short*)shape_p)[2 * tid];
    union { unsigned short u; __hip_bfloat16 b; } cv; cv.u = h;
    float v = fabsf(__bfloat162float(cv.b));
    if (v != v) v = 3.4e38f;
    mx[tid] = v;
    __syncthreads();
    if (tid == 0) {
        float m = 0.f;
        for (int i = 0; i < 64; ++i) m = fmaxf(m, mx[i]);
        flags[0] = (m > 1e4f) ? 1 : 0;
        int i64 = 1;
        const int* q = (const int*)lmk_idx;
        for (int i = 0; i < 25; ++i) if (q[2*i+1] != 0) i64 = 0;
        flags[1] = i64;
    }
}

// Pack B panel as bf16: Wb[n][k], k<400 shapedirs, 400..435 posedirs^T, else 0.
__global__ __launch_bounds__(448) void k_cvt(const void* __restrict__ shapedirs,
                                             const void* __restrict__ posedirs,
                                             const int* __restrict__ flags,
                                             __hip_bfloat16* __restrict__ Wb) {
    int f32 = flags[0];
    int n = blockIdx.x, k = threadIdx.x;
    float val = 0.f;
    if (n < N3) {
        if (k < KBETA)       val = ldf(shapedirs, (long)n*KBETA + k, f32);
        else if (k < 436)    val = ldf(posedirs, (long)(k-400)*N3 + n, f32);
    }
    Wb[(long)n*KTOT + k] = __float2bfloat16(val);
}

// JS[j][k][l] = sum_v Jreg[j][v]*shapedirs[v][k][l]; baseJ = Jreg @ v_template
__global__ void k_js(const void* __restrict__ Jreg,
                     const void* __restrict__ shapedirs,
                     const void* __restrict__ v_template,
                     const int* __restrict__ flags,
                     float* __restrict__ JS, float* __restrict__ baseJ) {
    int f32 = flags[0];
    int k = blockIdx.x;        // 0..2
    int vc = blockIdx.y;       // 0..63
    int tid = threadIdx.x;     // 0..255
    int v0 = vc * 79, v1 = min(NV, v0 + 79);
    int l2 = tid + 256;        // second l; 400 == template col
    float acc1[NJOINT] = {0,0,0,0,0};
    float acc2[NJOINT] = {0,0,0,0,0};
#pragma unroll 2
    for (int v = v0; v < v1; ++v) {
        float s1 = ldf(shapedirs, (long)v*1200 + k*400 + tid, f32);
        float s2 = 0.f;
        if (l2 < 400)       s2 = ldf(shapedirs, (long)v*1200 + k*400 + l2, f32);
        else if (l2 == 400) s2 = ldf(v_template, v*3 + k, f32);
#pragma unroll
        for (int j = 0; j < NJOINT; ++j) {
            float jr = ldf(Jreg, j*NV + v, f32);
            acc1[j] += jr * s1;
            acc2[j] += jr * s2;
        }
    }
#pragma unroll
    for (int j = 0; j < NJOINT; ++j) {
        atomicAdd(&JS[j*1200 + k*400 + tid], acc1[j]);
        if (l2 < 400)       atomicAdd(&JS[j*1200 + k*400 + l2], acc2[j]);
        else if (l2 == 400) atomicAdd(&baseJ[j*3 + k], acc2[j]);
    }
}

// Per-batch: betas->Act(bf16), joints, rodrigues, chain, A matrices, reg
__global__ __launch_bounds__(64) void k_batch(
        const void* __restrict__ shape_p, const void* __restrict__ expr_p,
        const void* __restrict__ grot, const void* __restrict__ neck,
        const void* __restrict__ jaw,  const void* __restrict__ eye,
        const float* __restrict__ JS, const float* __restrict__ baseJ,
        const int* __restrict__ flags,
        __hip_bfloat16* __restrict__ Act, float* __restrict__ Amat, float* __restrict__ reg) {
    int f32 = flags[0];
    int b = blockIdx.x, tid = threadIdx.x;
    __shared__ float betas[400];
    __shared__ float Rm[NJOINT][9];
    __shared__ float joints[NJOINT][3];
    __shared__ float Gm[NJOINT][12];

    for (int i = tid; i < 400; i += 64) {
        float v = (i < 300) ? ldf(shape_p, b*300 + i, f32)
                            : ldf(expr_p, b*100 + i - 300, f32);
        betas[i] = v;
        Act[b*KTOT + i] = __float2bfloat16(v);
    }
    if (tid >= 36 && tid < 48) Act[b*KTOT + 400 + tid] = __float2bfloat16(0.f);
    __syncthreads();

    // joints: 60 lanes = 15 outputs x 4-way K-split, shuffle-combined
    if (tid < 60) {
        int o = tid % 15, q = tid / 15;
        int j = o / 3, kk = o - 3*j;
        const float* js = &JS[j*1200 + kk*400 + q*100];
        float s = 0.f;
        for (int l = 0; l < 100; ++l) s += js[l] * betas[q*100 + l];
        s += __shfl_down(s, 15);
        s += __shfl_down(s, 30);
        if (q == 0) joints[j][kk] = s + baseJ[o];
    }
    if (tid < NJOINT) {
        int j = tid;
        float r[3];
        for (int c = 0; c < 3; ++c) {
            if (j == 0)      r[c] = ldf(grot, b*3 + c, f32);
            else if (j == 1) r[c] = ldf(neck, b*3 + c, f32);
            else if (j == 2) r[c] = ldf(jaw,  b*3 + c, f32);
            else if (j == 3) r[c] = ldf(eye,  b*6 + c, f32);
            else             r[c] = ldf(eye,  b*6 + 3 + c, f32);
        }
        float a0 = r[0] + 1e-8f, a1 = r[1] + 1e-8f, a2 = r[2] + 1e-8f;
        float angle = sqrtf(a0*a0 + a1*a1 + a2*a2);
        float inv = 1.0f / angle;
        float rx = r[0]*inv, ry = r[1]*inv, rz = r[2]*inv;
        float s = sinf(angle), c = cosf(angle);
        float K[9] = {0.f, -rz, ry,  rz, 0.f, -rx,  -ry, rx, 0.f};
        float K2[9];
        for (int rr = 0; rr < 3; ++rr)
            for (int cc = 0; cc < 3; ++cc) {
                float t = 0.f;
                for (int m = 0; m < 3; ++m) t += K[rr*3+m] * K[m*3+cc];
                K2[rr*3+cc] = t;
            }
        for (int i2 = 0; i2 < 9; ++i2) {
            float id = (i2 == 0 || i2 == 4 || i2 == 8) ? 1.f : 0.f;
            Rm[j][i2] = id + s*K[i2] + (1.f - c)*K2[i2];
        }
    }
    __syncthreads();

    if (tid < 36) {
        int i = tid / 9 + 1, rc = tid - (tid/9)*9;
        float id = (rc == 0 || rc == 4 || rc == 8) ? 1.f : 0.f;
        Act[b*KTOT + 400 + tid] = __float2bfloat16(Rm[i][rc] - id);
    }
    if (tid == 0) {
        for (int rr = 0; rr < 3; ++rr) {
            for (int cc = 0; cc < 3; ++cc) Gm[0][rr*4+cc] = Rm[0][rr*3+cc];
            Gm[0][rr*4+3] = joints[0][rr];
        }
        const int par[NJOINT] = {-1, 0, 1, 1, 1};
        for (int j = 1; j < NJOINT; ++j) {
            int p = par[j];
            float rel[3];
            for (int c2 = 0; c2 < 3; ++c2) rel[c2] = joints[j][c2] - joints[p][c2];
            for (int rr = 0; rr < 3; ++rr) {
                for (int cc = 0; cc < 3; ++cc) {
                    float t = 0.f;
                    for (int m = 0; m < 3; ++m) t += Gm[p][rr*4+m] * Rm[j][m*3+cc];
                    Gm[j][rr*4+cc] = t;
                }
                float t = Gm[p][rr*4+3];
                for (int m = 0; m < 3; ++m) t += Gm[p][rr*4+m] * rel[m];
                Gm[j][rr*4+3] = t;
            }
        }
    }
    __syncthreads();

    if (tid < 60) {
        int j = tid / 12, e = tid - j*12, rr = e / 4, cc = e - rr*4;
        float val = Gm[j][e];
        if (cc == 3)
            for (int m = 0; m < 3; ++m) val -= Gm[j][rr*4+m] * joints[j][m];
        Amat[b*60 + tid] = val;
    }

    float part = 0.f;
    for (int i = tid; i < 400; i += 64) part += betas[i]*betas[i];
    part *= 0.001f;
    if (tid == 0) {
        float nn = 0.f, jj = 0.f;
        for (int c = 0; c < 3; ++c) {
            float nv = ldf(neck, b*3+c, f32);
            float jv = ldf(jaw,  b*3+c, f32);
            nn += nv*nv; jj += jv*jj*0.f + jv*jv;
        }
        part += 100.f*nn + 0.001f*jj;
    }
    for (int off = 32; off; off >>= 1) part += __shfl_down(part, off);
    if (tid == 0) atomicAdd(reg, part);
}

// Fused GEMM + LBS, barrier-free K-loop, register-direct fragments.
// FULLB=1: B from packed bf16 Wb[n][448]. FULLB=0: B from raw shapedirs
// (s<12) + LDS tail tile Bs2.
template<int FULLB>
__global__ __launch_bounds__(256) void k_gemm_lbs(
        const __hip_bfloat16* __restrict__ Act,
        const __hip_bfloat16* __restrict__ Wb,
        const void* __restrict__ shapedirs,
        const void* __restrict__ posedirs,
        const void* __restrict__ v_template,
        const float* __restrict__ Amat,
        const void* __restrict__ weights,
        const void* __restrict__ transl,
        const int* __restrict__ flags,
        void* __restrict__ out) {
    __shared__ float tile[64 * LDP];                    // 13.3 KB
    __shared__ float Al[64 * 60];                       // 15.4 KB
    __shared__ float wl[16 * NJOINT];
    __shared__ __align__(16) __hip_bfloat16 Bs2[FULLB ? 64 : BN * 64];

    int f32 = flags[0];
    int tid = threadIdx.x;
    int wave = tid >> 6, lane = tid & 63;
    int fr = lane & 15, quad = lane >> 4;
    int m0 = blockIdx.x * BM;           // 4 m-blocks (fast-varying for L2 reuse)
    int n0 = blockIdx.y * BN;           // 314 n-blocks
    int v0 = blockIdx.y * 16;

    if (tid < 80) {
        int v = v0 + tid / NJOINT;
        wl[tid] = (v < NV) ? ldf(weights, v * NJOINT + tid % NJOINT, f32) : 0.f;
    }
    if (!FULLB) {
        for (int i = tid; i < BN * 64; i += 256) {
            int n = i >> 6, kk = i & 63;
            int nc = min(n0 + n, N3 - 1);
            float val = 0.f;
            if (kk < 16)      val = ldf(shapedirs, (long)nc*KBETA + 384 + kk, f32);
            else if (kk < 52) val = ldf(posedirs, (long)(kk-16)*N3 + nc, f32);
            Bs2[n*64 + kk] = __float2bfloat16(val);
        }
        __syncthreads();
    }

    // A row bases: wave handles 64 batch rows (4 subtiles of 16)
    const __hip_bfloat16* arow[4];
#pragma unroll
    for (int sub = 0; sub < 4; ++sub)
        arow[sub] = Act + (long)(m0 + wave*64 + sub*16 + fr) * KTOT;
    // B row indices (clamped)
    int nr[3];
#pragma unroll
    for (int t = 0; t < 3; ++t) nr[t] = min(n0 + t*16 + fr, N3 - 1);

    floatx4 acc[4][3];
#pragma unroll
    for (int sub = 0; sub < 4; ++sub)
#pragma unroll
        for (int t = 0; t < 3; ++t) acc[sub][t] = (floatx4){0.f,0.f,0.f,0.f};

#pragma unroll
    for (int s = 0; s < 14; ++s) {
        short8 bb[3];
#pragma unroll
        for (int t = 0; t < 3; ++t) {
            if (FULLB)
                bb[t] = *(const short8*)(Wb + (long)nr[t]*KTOT + s*32 + quad*8);
            else if (s < 12)
                bb[t] = ld8bf(shapedirs, (long)nr[t]*KBETA + s*32 + quad*8, f32);
            else
                bb[t] = *(short8*)&Bs2[(t*16 + fr)*64 + (s-12)*32 + quad*8];
        }
#pragma unroll
        for (int sub = 0; sub < 4; ++sub) {
            short8 a = *(const short8*)(arow[sub] + s*32 + quad*8);
#pragma unroll
            for (int t = 0; t < 3; ++t)
                acc[sub][t] = __builtin_amdgcn_mfma_f32_16x16x32_bf16(a, bb[t], acc[sub][t], 0, 0, 0);
        }
    }

    // Epilogue: 4 passes of 64 batch rows (wave p's accumulators)
    int vloc = tid & 15, mrow = tid >> 4;
    int v = v0 + vloc;
    float tpl0 = 0.f, tpl1 = 0.f, tpl2 = 0.f;
    if (v < NV) {
        tpl0 = ldf(v_template, v*3 + 0, f32);
        tpl1 = ldf(v_template, v*3 + 1, f32);
        tpl2 = ldf(v_template, v*3 + 2, f32);
    }
    for (int p = 0; p < 4; ++p) {
        __syncthreads();
        if (wave == p) {
#pragma unroll
            for (int sub = 0; sub < 4; ++sub)
#pragma unroll
                for (int t = 0; t < 3; ++t)
#pragma unroll
                    for (int rr = 0; rr < 4; ++rr)
                        tile[(sub*16 + quad*4 + rr)*LDP + t*16 + fr] = acc[sub][t][rr];
        }
        for (int i = tid; i < 64 * 60; i += 256) Al[i] = Amat[(m0 + p*64)*60 + i];
        __syncthreads();
        if (v >= NV) continue;
        float w0 = wl[vloc*NJOINT+0], w1 = wl[vloc*NJOINT+1], w2 = wl[vloc*NJOINT+2];
        float w3 = wl[vloc*NJOINT+3], w4 = wl[vloc*NJOINT+4];
#pragma unroll
        for (int it = 0; it < 4; ++it) {
            int mloc = mrow + 16*it;
            int m = m0 + p*64 + mloc;
            float p0 = tile[mloc*LDP + vloc*3 + 0] + tpl0;
            float p1 = tile[mloc*LDP + vloc*3 + 1] + tpl1;
            float p2 = tile[mloc*LDP + vloc*3 + 2] + tpl2;
            const float* A = &Al[mloc*60];
#pragma unroll
            for (int c = 0; c < 3; ++c) {
                float t0 = w0*A[c*4+0] + w1*A[12+c*4+0] + w2*A[24+c*4+0] + w3*A[36+c*4+0] + w4*A[48+c*4+0];
                float t1 = w0*A[c*4+1] + w1*A[12+c*4+1] + w2*A[24+c*4+1] + w3*A[36+c*4+1] + w4*A[48+c*4+1];
                float t2 = w0*A[c*4+2] + w1*A[12+c*4+2] + w2*A[24+c*4+2] + w3*A[36+c*4+2] + w4*A[48+c*4+2];
                float t3 = w0*A[c*4+3] + w1*A[12+c*4+3] + w2*A[24+c*4+3] + w3*A[36+c*4+3] + w4*A[48+c*4+3];
                float val = t0*p0 + t1*p1 + t2*p2 + t3 + ldf(transl, m*3 + c, f32);
                stf(out, ((long)m*NV + v)*3 + c, val, f32);
            }
        }
    }
}

// Landmarks from final vertices, plus flame_reg scalar.
__global__ __launch_bounds__(64) void k_lmk(const void* __restrict__ verts,
                                            const void* __restrict__ bary,
                                            const int* __restrict__ faces,
                                            const void* __restrict__ lmk_idx,
                                            const void* __restrict__ transl,
                                            const float* __restrict__ reg,
                                            const int* __restrict__ flags,
                                            void* __restrict__ out) {
    int f32 = flags[0], i64 = flags[1];
    int b = blockIdx.x, tid = threadIdx.x;
    if (b == 0 && tid == 63)
        stf(out, (long)BATCH*NV*3 + (long)BATCH*NLMK*3, reg[0], f32);
    if (tid >= NLMK) return;
    int f = i64 ? (int)((const long long*)lmk_idx)[tid]
                : ((const int*)lmk_idx)[tid];
    float acc[3] = {0.f, 0.f, 0.f};
    float bsum = 0.f;
    for (int fi = 0; fi < 3; ++fi) {
        int vi = faces[f*3 + fi];
        float bc = ldf(bary, tid*3 + fi, f32);
        bsum += bc;
#pragma unroll
        for (int c = 0; c < 3; ++c)
            acc[c] += bc * ldf(verts, ((long)b*NV + vi)*3 + c, f32);
    }
#pragma unroll
    for (int c = 0; c < 3; ++c) {
        float val = acc[c] + (1.f - bsum) * ldf(transl, b*3 + c, f32);
        stf(out, (long)BATCH*NV*3 + ((long)b*NLMK + tid)*3 + c, val, f32);
    }
}

extern "C" void kernel_launch(void* const* d_in, const int* in_sizes, int n_in,
                              void* d_out, int out_size, void* d_ws, size_t ws_size,
                              hipStream_t stream) {
    const void* shape_p   = d_in[0];
    const void* expr_p    = d_in[1];
    const void* grot      = d_in[2];
    const void* neck      = d_in[3];
    const void* jaw       = d_in[4];
    const void* eye       = d_in[5];
    const void* transl    = d_in[6];
    const void* v_templ   = d_in[7];
    const void* shapedirs = d_in[8];
    const void* posedirs  = d_in[9];
    const void* Jreg      = d_in[10];
    const void* weights   = d_in[11];
    const void* bary      = d_in[12];
    const int*  faces     = (const int*)d_in[14];
    const void* lmk_idx   = d_in[15];

    char* ws = (char*)d_ws;
    float* JS      = (float*)(ws + WS_JS);
    float* baseJ   = (float*)(ws + WS_BASEJ);
    float* reg     = (float*)(ws + WS_REG);
    int*   flags   = (int*)(ws + WS_FLAGS);
    float* Amat    = (float*)(ws + WS_AMAT);
    __hip_bfloat16* Act = (__hip_bfloat16*)(ws + WS_ACT);
    __hip_bfloat16* Wb  = (__hip_bfloat16*)(ws + WS_WB);
    bool big = ws_size >= (size_t)WS_FULL;

    k_zero<<<24, 256, 0, stream>>>((float*)ws, 6144);
    k_probe<<<1, 64, 0, stream>>>(shape_p, lmk_idx, flags);
    if (big) k_cvt<<<NPADB, 448, 0, stream>>>(shapedirs, posedirs, flags, Wb);
    k_js<<<dim3(3, 64), 256, 0, stream>>>(Jreg, shapedirs, v_templ, flags, JS, baseJ);
    k_batch<<<BATCH, 64, 0, stream>>>(shape_p, expr_p, grot, neck, jaw, eye,
                                      JS, baseJ, flags, Act, Amat, reg);
    dim3 grid(BATCH/BM, (N3 + BN - 1)/BN);
    if (big)
        k_gemm_lbs<1><<<grid, 256, 0, stream>>>(Act, Wb, shapedirs, posedirs, v_templ,
                                                Amat, weights, transl, flags, d_out);
    else
        k_gemm_lbs<0><<<grid, 256, 0, stream>>>(Act, Wb, shapedirs, posedirs, v_templ,
                                                Amat, weights, transl, flags, d_out);
    k_lmk<<<BATCH, 64, 0, stream>>>(d_out, bary, faces, lmk_idx, transl, reg, flags, d_out);
}